// Round 5
// baseline (272.167 us; speedup 1.0000x reference)
//
#include <hip/hip_runtime.h>
#include <math.h>

#define BB 16
#define TT 4096
#define CC 128

// Chunked scan: L-sized output chunks, W-step cold-start warmup (proven
// structure: absmax bit-identical 0.0625 at W=512/384/96/48).
//
// R14 change: class-force pf into ARCH VGPRs via inline-asm v_pk_fma_f32.
// Evidence R10-R13: VGPR_Count always << live set (pf=128 regs), and
// VALU-cycle delta between G=4 and G=2 = ~11 cyc per pf-f2-use (vs 2-4
// for a clean pk_fma) -> pf lives in AGPRs (intrinsic FMAs give AV-class
// ranges; allocator may park them there) and every use pays copies.
// waves_per_eu/launch_bounds hints did NOT move it. Inline-asm "v"
// constraints are strictly VGPR-class -> pf ranges become VReg_64 and
// CANNOT be AGPR-assigned; budget (waves_per_eu(1,2) -> 512 regs) vs
// ~220 needed means no split/spill either.
// Geometry = best-measured (R10/R11/R13): G=4 states/thread, 128-thread
// blocks (2 waves), LCH=128 -> grid 1024 = 4 blocks/CU, NS=175 steps.
#define LCH 128
#define WCH 48
#define NCH (TT / LCH)   // 32 chunks per chain

// Padded e-chunk stride: 36 floats (144 B) staggers the 4 broadcast read
// addresses across banks 0/4/8/12 (R6->R7: conflicts 1.28e8 -> 0).
#define EST 36

typedef float f2 __attribute__((ext_vector_type(2)));

// ---------------------------------------------------------------------------
// ws layout (floats):
//   [0,            CC*CC)              P   (row-major, softmax(log_trans) rows)
//   [CC*CC,        2*CC*CC)            PT  (transpose of P)
//   [2*CC*CC,      2*CC*CC + BB*TT*CC) beta
// ---------------------------------------------------------------------------

__device__ __forceinline__ float wave_reduce_max(float v) {
#pragma unroll
    for (int o = 1; o < 64; o <<= 1) v = fmaxf(v, __shfl_xor(v, o, 64));
    return v;
}
__device__ __forceinline__ float wave_reduce_sum(float v) {
#pragma unroll
    for (int o = 1; o < 64; o <<= 1) v += __shfl_xor(v, o, 64);
    return v;
}

// LDS-only barrier: skip the compiler's conservative s_waitcnt vmcnt(0)
// before s_barrier so global prefetch/stores stay in flight.
__device__ __forceinline__ void lds_barrier() {
    __asm__ __volatile__("s_waitcnt lgkmcnt(0)" ::: "memory");
    __builtin_amdgcn_s_barrier();
}

// Quad-perm butterfly add via DPP: cross-lane xor over lane bits 0-1 on the
// VALU pipe. 0xB1 = quad_perm(1,0,3,2) (xor 1), 0x4E = quad_perm(2,3,0,1).
template <int CTRL>
__device__ __forceinline__ float qadd(float v) {
    int o = __builtin_amdgcn_update_dpp(0, __float_as_int(v), CTRL, 0xF, 0xF, true);
    return v + __int_as_float(o);
}

// Packed f32 ops as inline asm: "v" constraints pin ALL operands (incl. the
// pf fragment) to arch-VGPR register class. D/A/B are f2 (64-bit pairs).
#define PK_MUL(D, A, B)                                                        \
    __asm__("v_pk_mul_f32 %0, %1, %2" : "=v"(D) : "v"(A), "v"(B))
#define PK_FMA(D, A, B)                                                        \
    __asm__("v_pk_fma_f32 %0, %1, %2, %0" : "+v"(D) : "v"(A), "v"(B))

// ---- pf: 4 rows x 16 f2 as named values + asm pin ----
#define PF_DECL(rr)                                                            \
    f2 pf_##rr##_0, pf_##rr##_1, pf_##rr##_2, pf_##rr##_3, pf_##rr##_4,        \
        pf_##rr##_5, pf_##rr##_6, pf_##rr##_7, pf_##rr##_8, pf_##rr##_9,       \
        pf_##rr##_10, pf_##rr##_11, pf_##rr##_12, pf_##rr##_13, pf_##rr##_14,  \
        pf_##rr##_15

#define PF_LOAD(rr)                                                            \
    do {                                                                       \
        const float4* grow =                                                   \
            (const float4*)(gbase + (j4 + rr) * CC + q * 32);                  \
        float4 v;                                                              \
        v = grow[0]; pf_##rr##_0  = f2{v.x, v.y}; pf_##rr##_1  = f2{v.z, v.w}; \
        v = grow[1]; pf_##rr##_2  = f2{v.x, v.y}; pf_##rr##_3  = f2{v.z, v.w}; \
        v = grow[2]; pf_##rr##_4  = f2{v.x, v.y}; pf_##rr##_5  = f2{v.z, v.w}; \
        v = grow[3]; pf_##rr##_6  = f2{v.x, v.y}; pf_##rr##_7  = f2{v.z, v.w}; \
        v = grow[4]; pf_##rr##_8  = f2{v.x, v.y}; pf_##rr##_9  = f2{v.z, v.w}; \
        v = grow[5]; pf_##rr##_10 = f2{v.x, v.y}; pf_##rr##_11 = f2{v.z, v.w}; \
        v = grow[6]; pf_##rr##_12 = f2{v.x, v.y}; pf_##rr##_13 = f2{v.z, v.w}; \
        v = grow[7]; pf_##rr##_14 = f2{v.x, v.y}; pf_##rr##_15 = f2{v.z, v.w}; \
    } while (0)

// Opaque pin: asm outputs are fresh defs -> backend cannot re-materialize
// the global loads inside the loop.
#define PF_PIN(rr)                                                             \
    __asm__ volatile(""                                                        \
                     : "+v"(pf_##rr##_0), "+v"(pf_##rr##_1), "+v"(pf_##rr##_2),\
                       "+v"(pf_##rr##_3), "+v"(pf_##rr##_4), "+v"(pf_##rr##_5),\
                       "+v"(pf_##rr##_6), "+v"(pf_##rr##_7), "+v"(pf_##rr##_8),\
                       "+v"(pf_##rr##_9), "+v"(pf_##rr##_10),                  \
                       "+v"(pf_##rr##_11), "+v"(pf_##rr##_12),                 \
                       "+v"(pf_##rr##_13), "+v"(pf_##rr##_14),                 \
                       "+v"(pf_##rr##_15))

// Dot of row rr against the 32-float e-chunk: two 8-deep chains, first op
// is a mul (no zero-init movs), all via asm -> operands VGPR-class.
#define ROW_DOT(rr, OUT)                                                       \
    do {                                                                       \
        f2 aA, aB;                                                             \
        PK_MUL(aA, e01_0, pf_##rr##_0);                                        \
        PK_MUL(aB, e23_0, pf_##rr##_1);                                        \
        PK_FMA(aA, e01_1, pf_##rr##_2);                                        \
        PK_FMA(aB, e23_1, pf_##rr##_3);                                        \
        PK_FMA(aA, e01_2, pf_##rr##_4);                                        \
        PK_FMA(aB, e23_2, pf_##rr##_5);                                        \
        PK_FMA(aA, e01_3, pf_##rr##_6);                                        \
        PK_FMA(aB, e23_3, pf_##rr##_7);                                        \
        PK_FMA(aA, e01_4, pf_##rr##_8);                                        \
        PK_FMA(aB, e23_4, pf_##rr##_9);                                        \
        PK_FMA(aA, e01_5, pf_##rr##_10);                                       \
        PK_FMA(aB, e23_5, pf_##rr##_11);                                       \
        PK_FMA(aA, e01_6, pf_##rr##_12);                                       \
        PK_FMA(aB, e23_6, pf_##rr##_13);                                       \
        PK_FMA(aA, e01_7, pf_##rr##_14);                                       \
        PK_FMA(aB, e23_7, pf_##rr##_15);                                       \
        f2 s2 = aA + aB;                                                       \
        OUT = (s2.x + s2.y) * fs;                                              \
    } while (0)

// ---------------------------------------------------------------------------
// Prep: P = exp(log_softmax(log_trans, axis=1)); also PT = P^T.
// ---------------------------------------------------------------------------
__global__ __launch_bounds__(CC) void prep_kernel(const float* __restrict__ lt,
                                                  float* __restrict__ P,
                                                  float* __restrict__ PT) {
    const int r  = blockIdx.x;
    const int j  = threadIdx.x;
    const int wv = j >> 6;
    __shared__ float sm[2];

    float x = lt[r * CC + j];
    float m = wave_reduce_max(x);
    if ((j & 63) == 0) sm[wv] = m;
    __syncthreads();
    m = fmaxf(sm[0], sm[1]);
    __syncthreads();
    float e = __expf(x - m);
    float s = wave_reduce_sum(e);
    if ((j & 63) == 0) sm[wv] = s;
    __syncthreads();
    s = sm[0] + sm[1];
    float p = e / s;
    P[r * CC + j]  = p;
    PT[j * CC + r] = p;
}

// ---------------------------------------------------------------------------
// Chunked scan, ONE barrier per step.
// Grid = 2*BB*NCH = 1024 blocks of 128 threads (2 waves) = 4 blocks/CU.
//   id < BB*NCH  : forward chunk  (alpha -> d_out)
//   id >= BB*NCH : backward chunk (beta  -> ws)
// Thread t: quarter q = t&3 (i-range [32q,32q+32)), group g = t>>2 owning
// states 4g..4g+3. pf = 4 rows x 16 f2 = 128 floats, arch-VGPR resident
// (asm "v"-class uses + waves_per_eu(1,2) budget).
// The 4 q-copies of a group are consecutive lanes -> DPP quad combine.
// e stored padded: group g at ebuf[(g>>3)*EST + (g&7)*4] (float4 write by
// q==0). ebuf/wbuf parity-double-buffered (1 barrier/step).
// Scale fixup: chunk [32q,32q+32) is produced entirely by wave q>>1, so
// one factor exp(w[q>>1]-w[0]) per thread, applied inside ROW_DOT.
// Dropped per-row constants die in the final log_softmax.
// ---------------------------------------------------------------------------
__global__
__attribute__((amdgpu_flat_work_group_size(128, 128)))
__attribute__((amdgpu_waves_per_eu(1, 2)))
void scan_kernel(const float* __restrict__ u,
                 const float* __restrict__ Pm,
                 const float* __restrict__ PT,
                 float* __restrict__ alpha,
                 float* __restrict__ beta) {
    const int t  = threadIdx.x;   // 0..127
    const int q  = t & 3;
    const int g  = t >> 2;        // 0..31
    const int j4 = g << 2;        // first of 4 owned states

    const int  id  = blockIdx.x;
    const bool fwd = id < BB * NCH;
    const int  r   = fwd ? id : id - BB * NCH;
    const int  b   = r >> 5;             // NCH = 32
    const int  c   = r & (NCH - 1);

    __shared__ alignas(16) float ebuf[2][4 * EST];
    __shared__ alignas(16) float wbuf[2][2];

    // P fragment: rows j4..j4+3 of G = (fwd ? PT : P), i-chunk [32q, 32q+32).
    PF_DECL(0); PF_DECL(1); PF_DECL(2); PF_DECL(3);
    {
        const float* gbase = fwd ? PT : Pm;
        PF_LOAD(0); PF_LOAD(1); PF_LOAD(2); PF_LOAD(3);
    }
    PF_PIN(0); PF_PIN(1); PF_PIN(2); PF_PIN(3);

    const float* ub = u + (size_t)b * TT * CC;
    float*       ob = (fwd ? alpha : beta) + (size_t)b * TT * CC;

    const int wlo = c * LCH;
    const int whi = wlo + LCH;
    int t0 = 0, t1 = 0, NS;
    if (fwd) {
        t0 = wlo - WCH; if (t0 < 0) t0 = 0;
        NS = whi - 1 - t0;
    } else {
        t1 = whi - 1 + WCH; if (t1 > TT - 1) t1 = TT - 1;
        NS = t1 - wlo;
    }

    // Per-thread state for 4 states (4 redundant q-copies each).
    float4 st, u_cur, u_n1, u_n2, u_pf;
    if (fwd) {
        st = *(const float4*)(ub + t0 * CC + j4);           // exact when t0==0
        if (q == 0 && t0 == 0 && wlo == 0) *(float4*)(ob + j4) = st;
        u_cur = *(const float4*)(ub + (t0 + 1) * CC + j4);
        u_n1  = *(const float4*)(ub + (t0 + 2) * CC + j4);
        u_n2  = *(const float4*)(ub + (t0 + 3) * CC + j4);
    } else {
        st = float4{0.f, 0.f, 0.f, 0.f};                    // exact when t1==TT-1
        if (q == 0 && t1 == whi - 1) *(float4*)(ob + (size_t)t1 * CC + j4) = st;
        u_cur = *(const float4*)(ub + (size_t)(t1    ) * CC + j4);
        u_n1  = *(const float4*)(ub + (size_t)(t1 - 1) * CC + j4);
        u_n2  = *(const float4*)(ub + (size_t)(t1 - 2) * CC + j4);
    }

    const int epos = (g >> 3) * EST + (g & 7) * 4;  // padded float4 slot

    for (int s = 0; s < NS; ++s) {
        const int par = s & 1;

        // prefetch u row for step s+3 (clamped; extra loads harmless)
        int rpf;
        if (fwd) { rpf = t0 + 4 + s; if (rpf > TT - 1) rpf = TT - 1; }
        else     { rpf = t1 - 3 - s; if (rpf < 0)      rpf = 0; }
        u_pf = *(const float4*)(ub + (size_t)rpf * CC + j4);

        // fwd: x = alpha_{t-1};  bwd: x = beta_{t+1} + u_{t+1}
        float4 x;
        if (fwd) x = st;
        else     x = float4{st.x + u_cur.x, st.y + u_cur.y,
                            st.z + u_cur.z, st.w + u_cur.w};
        float w = __int_as_float(__builtin_amdgcn_readfirstlane(__float_as_int(x.x)));
        float4 e;
        e.x = __expf(x.x - w);
        e.y = __expf(x.y - w);
        e.z = __expf(x.z - w);
        e.w = __expf(x.w - w);
        if (q == 0) *(float4*)(&ebuf[par][epos]) = e;
        if ((t & 63) == 0) wbuf[par][t >> 6] = w;
        lds_barrier();  // e + w published (the ONLY barrier this step)

        // broadcast-read the 32-float e-chunk for quarter q (8 b128, banks
        // staggered by EST padding -> conflict-free)
        const float4* ec = (const float4*)(&ebuf[par][q * EST]);
        float4 ev0 = ec[0], ev1 = ec[1], ev2 = ec[2], ev3 = ec[3];
        float4 ev4 = ec[4], ev5 = ec[5], ev6 = ec[6], ev7 = ec[7];
        f2 e01_0 = f2{ev0.x, ev0.y}, e23_0 = f2{ev0.z, ev0.w};
        f2 e01_1 = f2{ev1.x, ev1.y}, e23_1 = f2{ev1.z, ev1.w};
        f2 e01_2 = f2{ev2.x, ev2.y}, e23_2 = f2{ev2.z, ev2.w};
        f2 e01_3 = f2{ev3.x, ev3.y}, e23_3 = f2{ev3.z, ev3.w};
        f2 e01_4 = f2{ev4.x, ev4.y}, e23_4 = f2{ev4.z, ev4.w};
        f2 e01_5 = f2{ev5.x, ev5.y}, e23_5 = f2{ev5.z, ev5.w};
        f2 e01_6 = f2{ev6.x, ev6.y}, e23_6 = f2{ev6.z, ev6.w};
        f2 e01_7 = f2{ev7.x, ev7.y}, e23_7 = f2{ev7.z, ev7.w};

        // scale fixup: this thread's whole i-chunk was produced by wave q>>1
        f2    wpair = *((const f2*)&wbuf[par][0]);
        float wg = (q >= 2) ? wpair.y : wpair.x;
        float fs = __expf(wg - wpair.x);   // == 1.0 for q<2

        float4 sp;
        ROW_DOT(0, sp.x);
        ROW_DOT(1, sp.y);
        ROW_DOT(2, sp.z);
        ROW_DOT(3, sp.w);

        // combine the 4 quarters (consecutive lanes) on the VALU pipe
        sp.x = qadd<0x4E>(qadd<0xB1>(sp.x));
        sp.y = qadd<0x4E>(qadd<0xB1>(sp.y));
        sp.z = qadd<0x4E>(qadd<0xB1>(sp.z));
        sp.w = qadd<0x4E>(qadd<0xB1>(sp.w));

        float4 L;
        L.x = __logf(sp.x);
        L.y = __logf(sp.y);
        L.z = __logf(sp.z);
        L.w = __logf(sp.w);
        if (fwd) st = float4{u_cur.x + L.x, u_cur.y + L.y,
                             u_cur.z + L.z, u_cur.w + L.w};
        else     st = L;

        int  trow = fwd ? (t0 + 1 + s) : (t1 - 1 - s);
        bool wr   = fwd ? (trow >= wlo) : (trow < whi);
        if (q == 0 && wr) *(float4*)(ob + (size_t)trow * CC + j4) = st;

        u_cur = u_n1; u_n1 = u_n2; u_n2 = u_pf;
    }
}

// ---------------------------------------------------------------------------
// Combine: out = log_softmax(alpha + beta, axis=-1), in place over d_out.
// float4 per lane; each 32-lane half-wave owns one row (128 floats).
// ---------------------------------------------------------------------------
__global__ __launch_bounds__(256) void combine_kernel(float* __restrict__ out,
                                                      const float* __restrict__ beta) {
    const int    lane = threadIdx.x & 63;
    const int    li   = lane & 31;
    const size_t row  = (size_t)blockIdx.x * 8 + ((threadIdx.x >> 6) << 1) + (lane >> 5);

    float4*       o4 = (float4*)(out + row * CC);
    const float4* b4 = (const float4*)(beta + row * CC);

    float4 a = o4[li];
    float4 bb = b4[li];
    float4 z = float4{a.x + bb.x, a.y + bb.y, a.z + bb.z, a.w + bb.w};

    float m = fmaxf(fmaxf(z.x, z.y), fmaxf(z.z, z.w));
#pragma unroll
    for (int o = 1; o < 32; o <<= 1) m = fmaxf(m, __shfl_xor(m, o, 64));
    float s = __expf(z.x - m) + __expf(z.y - m) + __expf(z.z - m) + __expf(z.w - m);
#pragma unroll
    for (int o = 1; o < 32; o <<= 1) s += __shfl_xor(s, o, 64);
    float ls = m + __logf(s);
    o4[li] = float4{z.x - ls, z.y - ls, z.z - ls, z.w - ls};
}

// ---------------------------------------------------------------------------
extern "C" void kernel_launch(void* const* d_in, const int* in_sizes, int n_in,
                              void* d_out, int out_size, void* d_ws, size_t ws_size,
                              hipStream_t stream) {
    const float* u_in = (const float*)d_in[0];   // (B, T, C) fp32
    const float* lt   = (const float*)d_in[1];   // (C, C)    fp32
    float*       out  = (float*)d_out;           // (B, T, C) fp32

    float* P    = (float*)d_ws;
    float* PT   = P + CC * CC;
    float* beta = PT + CC * CC;

    prep_kernel<<<CC, CC, 0, stream>>>(lt, P, PT);
    scan_kernel<<<2 * BB * NCH, 128, 0, stream>>>(u_in, P, PT, out, beta);
    combine_kernel<<<(BB * TT) / 8, 256, 0, stream>>>(out, beta);
}

// Round 6
// 264.525 us; speedup vs baseline: 1.0289x; 1.0289x over previous
//
#include <hip/hip_runtime.h>
#include <math.h>

#define BB 16
#define TT 4096
#define CC 128

// Chunked scan: L-sized output chunks, W-step cold-start warmup (proven
// structure: absmax bit-identical 0.0625 at W=512/384/96/48).
//
// R15 change: concurrency, not codegen. R14's null (pure v_pk asm with "v"
// constraints -> identical time) killed the "force VGPR residency" axis:
// the allocator satisfies per-use constraints with copies. Clean cross-round
// signal (cyc per chain-step: R9=878@32w/CU, R12=943@8w/CU-2chain,
// R13=686@8w/CU-4chain) says per-step wall is 3-5x issue floor and tracks
// CONCURRENCY -> exposed per-step serial latency (ds_read ~120cyc, compiler
// vmcnt waits on the u stream, trans chains, barrier skew) that 2 lockstep
// waves/SIMD can't hide. Fix: R=2 rows/thread, Q=4 (pf=64 floats), 256-thr
// blocks (4 waves), LCH=128 -> 1024 blocks = 4 blocks/CU = 16 waves/CU =
// 4 waves/SIMD from 4 INDEPENDENT blocks (HW round-robins block waves
// across SIMDs). Demand ~120 regs <= 128 cap (launch_bounds(256,4)) -> no
// AGPR parking pressure (R9 at demand~60 was clean). u-pipeline 3-deep
// (prefetch 2 ahead; 2 steps x ~1300cyc covers HBM ~900).
#define LCH 128
#define WCH 48
#define NCH (TT / LCH)   // 32 chunks per chain

// Padded e-chunk stride: 36 floats (144 B) staggers the 4 broadcast read
// addresses across banks 0/4/8/12 (R6->R7: conflicts 1.28e8 -> 0).
#define EST 36

typedef float f2 __attribute__((ext_vector_type(2)));

// ---------------------------------------------------------------------------
// ws layout (floats):
//   [0,            CC*CC)              P   (row-major, softmax(log_trans) rows)
//   [CC*CC,        2*CC*CC)            PT  (transpose of P)
//   [2*CC*CC,      2*CC*CC + BB*TT*CC) beta
// ---------------------------------------------------------------------------

__device__ __forceinline__ float wave_reduce_max(float v) {
#pragma unroll
    for (int o = 1; o < 64; o <<= 1) v = fmaxf(v, __shfl_xor(v, o, 64));
    return v;
}
__device__ __forceinline__ float wave_reduce_sum(float v) {
#pragma unroll
    for (int o = 1; o < 64; o <<= 1) v += __shfl_xor(v, o, 64);
    return v;
}

// LDS-only barrier: skip the compiler's conservative s_waitcnt vmcnt(0)
// before s_barrier so global prefetch/stores stay in flight.
__device__ __forceinline__ void lds_barrier() {
    __asm__ __volatile__("s_waitcnt lgkmcnt(0)" ::: "memory");
    __builtin_amdgcn_s_barrier();
}

// Quad-perm butterfly add via DPP: cross-lane xor over lane bits 0-1 on the
// VALU pipe. 0xB1 = quad_perm(1,0,3,2) (xor 1), 0x4E = quad_perm(2,3,0,1).
template <int CTRL>
__device__ __forceinline__ float qadd(float v) {
    int o = __builtin_amdgcn_update_dpp(0, __float_as_int(v), CTRL, 0xF, 0xF, true);
    return v + __int_as_float(o);
}

// Packed f32 ops as inline asm (guaranteed pk instruction selection).
#define PK_MUL(D, A, B)                                                        \
    __asm__("v_pk_mul_f32 %0, %1, %2" : "=v"(D) : "v"(A), "v"(B))
#define PK_FMA(D, A, B)                                                        \
    __asm__("v_pk_fma_f32 %0, %1, %2, %0" : "+v"(D) : "v"(A), "v"(B))

// ---- pf: 2 rows x 16 f2 as named values + asm pin ----
#define PF_DECL(rr)                                                            \
    f2 pf_##rr##_0, pf_##rr##_1, pf_##rr##_2, pf_##rr##_3, pf_##rr##_4,        \
        pf_##rr##_5, pf_##rr##_6, pf_##rr##_7, pf_##rr##_8, pf_##rr##_9,       \
        pf_##rr##_10, pf_##rr##_11, pf_##rr##_12, pf_##rr##_13, pf_##rr##_14,  \
        pf_##rr##_15

#define PF_LOAD(rr)                                                            \
    do {                                                                       \
        const float4* grow =                                                   \
            (const float4*)(gbase + (j2 + rr) * CC + q * 32);                  \
        float4 v;                                                              \
        v = grow[0]; pf_##rr##_0  = f2{v.x, v.y}; pf_##rr##_1  = f2{v.z, v.w}; \
        v = grow[1]; pf_##rr##_2  = f2{v.x, v.y}; pf_##rr##_3  = f2{v.z, v.w}; \
        v = grow[2]; pf_##rr##_4  = f2{v.x, v.y}; pf_##rr##_5  = f2{v.z, v.w}; \
        v = grow[3]; pf_##rr##_6  = f2{v.x, v.y}; pf_##rr##_7  = f2{v.z, v.w}; \
        v = grow[4]; pf_##rr##_8  = f2{v.x, v.y}; pf_##rr##_9  = f2{v.z, v.w}; \
        v = grow[5]; pf_##rr##_10 = f2{v.x, v.y}; pf_##rr##_11 = f2{v.z, v.w}; \
        v = grow[6]; pf_##rr##_12 = f2{v.x, v.y}; pf_##rr##_13 = f2{v.z, v.w}; \
        v = grow[7]; pf_##rr##_14 = f2{v.x, v.y}; pf_##rr##_15 = f2{v.z, v.w}; \
    } while (0)

// Opaque pin: asm outputs are fresh defs -> backend cannot re-materialize
// the global loads inside the loop.
#define PF_PIN(rr)                                                             \
    __asm__ volatile(""                                                        \
                     : "+v"(pf_##rr##_0), "+v"(pf_##rr##_1), "+v"(pf_##rr##_2),\
                       "+v"(pf_##rr##_3), "+v"(pf_##rr##_4), "+v"(pf_##rr##_5),\
                       "+v"(pf_##rr##_6), "+v"(pf_##rr##_7), "+v"(pf_##rr##_8),\
                       "+v"(pf_##rr##_9), "+v"(pf_##rr##_10),                  \
                       "+v"(pf_##rr##_11), "+v"(pf_##rr##_12),                 \
                       "+v"(pf_##rr##_13), "+v"(pf_##rr##_14),                 \
                       "+v"(pf_##rr##_15))

// Dot of row rr against the 32-float e-chunk: two 8-deep chains, first op
// is a mul (no zero-init movs).
#define ROW_DOT(rr, OUT)                                                       \
    do {                                                                       \
        f2 aA, aB;                                                             \
        PK_MUL(aA, e01_0, pf_##rr##_0);                                        \
        PK_MUL(aB, e23_0, pf_##rr##_1);                                        \
        PK_FMA(aA, e01_1, pf_##rr##_2);                                        \
        PK_FMA(aB, e23_1, pf_##rr##_3);                                        \
        PK_FMA(aA, e01_2, pf_##rr##_4);                                        \
        PK_FMA(aB, e23_2, pf_##rr##_5);                                        \
        PK_FMA(aA, e01_3, pf_##rr##_6);                                        \
        PK_FMA(aB, e23_3, pf_##rr##_7);                                        \
        PK_FMA(aA, e01_4, pf_##rr##_8);                                        \
        PK_FMA(aB, e23_4, pf_##rr##_9);                                        \
        PK_FMA(aA, e01_5, pf_##rr##_10);                                       \
        PK_FMA(aB, e23_5, pf_##rr##_11);                                       \
        PK_FMA(aA, e01_6, pf_##rr##_12);                                       \
        PK_FMA(aB, e23_6, pf_##rr##_13);                                       \
        PK_FMA(aA, e01_7, pf_##rr##_14);                                       \
        PK_FMA(aB, e23_7, pf_##rr##_15);                                       \
        f2 s2 = aA + aB;                                                       \
        OUT = (s2.x + s2.y) * fs;                                              \
    } while (0)

// ---------------------------------------------------------------------------
// Prep: P = exp(log_softmax(log_trans, axis=1)); also PT = P^T.
// ---------------------------------------------------------------------------
__global__ __launch_bounds__(CC) void prep_kernel(const float* __restrict__ lt,
                                                  float* __restrict__ P,
                                                  float* __restrict__ PT) {
    const int r  = blockIdx.x;
    const int j  = threadIdx.x;
    const int wv = j >> 6;
    __shared__ float sm[2];

    float x = lt[r * CC + j];
    float m = wave_reduce_max(x);
    if ((j & 63) == 0) sm[wv] = m;
    __syncthreads();
    m = fmaxf(sm[0], sm[1]);
    __syncthreads();
    float e = __expf(x - m);
    float s = wave_reduce_sum(e);
    if ((j & 63) == 0) sm[wv] = s;
    __syncthreads();
    s = sm[0] + sm[1];
    float p = e / s;
    P[r * CC + j]  = p;
    PT[j * CC + r] = p;
}

// ---------------------------------------------------------------------------
// Chunked scan, ONE barrier per step.
// Grid = 2*BB*NCH = 1024 blocks of 256 threads (4 waves) = 4 blocks/CU
// = 16 waves/CU = 4 waves/SIMD from 4 independent blocks.
//   id < BB*NCH  : forward chunk  (alpha -> d_out)
//   id >= BB*NCH : backward chunk (beta  -> ws)
// Thread t: quarter q = t&3 (i-range [32q,32q+32)), group g = t>>2 in
// [0,64) owning states 2g, 2g+1. pf = 2 rows x 16 f2 = 64 VGPRs. The 4
// q-copies of a group are consecutive lanes -> DPP quad combine.
// e stored padded: state pair 2g at ebuf[(g>>4)*EST + (2g&31)] (f2 write
// by q==0). ebuf/wbuf parity-double-buffered (1 barrier/step).
// Scale fixup: chunk [32q,32q+32) = states of groups [16q,16q+16) = lanes
// of wave q exactly -> fs = exp(w[q]-w[0]), one exp/thread.
// Dropped per-row constants die in the final log_softmax.
// ---------------------------------------------------------------------------
__global__ __launch_bounds__(256, 4)
void scan_kernel(const float* __restrict__ u,
                 const float* __restrict__ Pm,
                 const float* __restrict__ PT,
                 float* __restrict__ alpha,
                 float* __restrict__ beta) {
    const int t  = threadIdx.x;   // 0..255
    const int q  = t & 3;
    const int g  = t >> 2;        // 0..63
    const int j2 = g << 1;        // first of 2 owned states

    const int  id  = blockIdx.x;
    const bool fwd = id < BB * NCH;
    const int  r   = fwd ? id : id - BB * NCH;
    const int  b   = r >> 5;             // NCH = 32
    const int  c   = r & (NCH - 1);

    __shared__ alignas(16) float ebuf[2][4 * EST];
    __shared__ alignas(16) float wbuf[2][4];

    // P fragment: rows j2..j2+1 of G = (fwd ? PT : P), i-chunk [32q, 32q+32).
    PF_DECL(0); PF_DECL(1);
    {
        const float* gbase = fwd ? PT : Pm;
        PF_LOAD(0); PF_LOAD(1);
    }
    PF_PIN(0); PF_PIN(1);

    const float* ub = u + (size_t)b * TT * CC;
    float*       ob = (fwd ? alpha : beta) + (size_t)b * TT * CC;

    const int wlo = c * LCH;
    const int whi = wlo + LCH;
    int t0 = 0, t1 = 0, NS;
    if (fwd) {
        t0 = wlo - WCH; if (t0 < 0) t0 = 0;
        NS = whi - 1 - t0;
    } else {
        t1 = whi - 1 + WCH; if (t1 > TT - 1) t1 = TT - 1;
        NS = t1 - wlo;
    }

    // Per-thread state for 2 states (4 redundant q-copies each).
    // 3-deep u pipeline: u_pf loaded at step s is consumed at step s+2.
    f2 st, u_cur, u_n1, u_pf;
    if (fwd) {
        st = *(const f2*)(ub + t0 * CC + j2);               // exact when t0==0
        if (q == 0 && t0 == 0 && wlo == 0) *(f2*)(ob + j2) = st;
        u_cur = *(const f2*)(ub + (t0 + 1) * CC + j2);
        u_n1  = *(const f2*)(ub + (t0 + 2) * CC + j2);
    } else {
        st = f2{0.f, 0.f};                                  // exact when t1==TT-1
        if (q == 0 && t1 == whi - 1) *(f2*)(ob + (size_t)t1 * CC + j2) = st;
        u_cur = *(const f2*)(ub + (size_t)(t1    ) * CC + j2);
        u_n1  = *(const f2*)(ub + (size_t)(t1 - 1) * CC + j2);
    }

    const int epos = (g >> 4) * EST + ((g << 1) & 31);  // padded f2 slot

    for (int s = 0; s < NS; ++s) {
        const int par = s & 1;

        // prefetch u row for step s+2 (clamped; extra loads harmless)
        int rpf;
        if (fwd) { rpf = t0 + 3 + s; if (rpf > TT - 1) rpf = TT - 1; }
        else     { rpf = t1 - 2 - s; if (rpf < 0)      rpf = 0; }
        u_pf = *(const f2*)(ub + (size_t)rpf * CC + j2);

        // fwd: x = alpha_{t-1};  bwd: x = beta_{t+1} + u_{t+1}
        f2 x = fwd ? st : (st + u_cur);
        float w = __int_as_float(__builtin_amdgcn_readfirstlane(__float_as_int(x.x)));
        f2 e;
        e.x = __expf(x.x - w);
        e.y = __expf(x.y - w);
        if (q == 0) *(f2*)(&ebuf[par][epos]) = e;
        if ((t & 63) == 0) wbuf[par][t >> 6] = w;
        lds_barrier();  // e + w published (the ONLY barrier this step)

        // broadcast-read the 32-float e-chunk for quarter q (8 b128, banks
        // staggered by EST padding -> conflict-free)
        const float4* ec = (const float4*)(&ebuf[par][q * EST]);
        float4 ev0 = ec[0], ev1 = ec[1], ev2 = ec[2], ev3 = ec[3];
        float4 ev4 = ec[4], ev5 = ec[5], ev6 = ec[6], ev7 = ec[7];
        f2 e01_0 = f2{ev0.x, ev0.y}, e23_0 = f2{ev0.z, ev0.w};
        f2 e01_1 = f2{ev1.x, ev1.y}, e23_1 = f2{ev1.z, ev1.w};
        f2 e01_2 = f2{ev2.x, ev2.y}, e23_2 = f2{ev2.z, ev2.w};
        f2 e01_3 = f2{ev3.x, ev3.y}, e23_3 = f2{ev3.z, ev3.w};
        f2 e01_4 = f2{ev4.x, ev4.y}, e23_4 = f2{ev4.z, ev4.w};
        f2 e01_5 = f2{ev5.x, ev5.y}, e23_5 = f2{ev5.z, ev5.w};
        f2 e01_6 = f2{ev6.x, ev6.y}, e23_6 = f2{ev6.z, ev6.w};
        f2 e01_7 = f2{ev7.x, ev7.y}, e23_7 = f2{ev7.z, ev7.w};

        // scale fixup: chunk q was produced entirely by wave q
        float w0 = wbuf[par][0];
        float wq = wbuf[par][q];
        float fs = __expf(wq - w0);        // == 1.0 for q == 0

        f2 sp;
        ROW_DOT(0, sp.x);
        ROW_DOT(1, sp.y);

        // combine the 4 quarters (consecutive lanes) on the VALU pipe
        sp.x = qadd<0x4E>(qadd<0xB1>(sp.x));
        sp.y = qadd<0x4E>(qadd<0xB1>(sp.y));

        f2 L;
        L.x = __logf(sp.x);
        L.y = __logf(sp.y);
        st = fwd ? (u_cur + L) : L;

        int  trow = fwd ? (t0 + 1 + s) : (t1 - 1 - s);
        bool wr   = fwd ? (trow >= wlo) : (trow < whi);
        if (q == 0 && wr) *(f2*)(ob + (size_t)trow * CC + j2) = st;

        u_cur = u_n1; u_n1 = u_pf;
    }
}

// ---------------------------------------------------------------------------
// Combine: out = log_softmax(alpha + beta, axis=-1), in place over d_out.
// float4 per lane; each 32-lane half-wave owns one row (128 floats).
// ---------------------------------------------------------------------------
__global__ __launch_bounds__(256) void combine_kernel(float* __restrict__ out,
                                                      const float* __restrict__ beta) {
    const int    lane = threadIdx.x & 63;
    const int    li   = lane & 31;
    const size_t row  = (size_t)blockIdx.x * 8 + ((threadIdx.x >> 6) << 1) + (lane >> 5);

    float4*       o4 = (float4*)(out + row * CC);
    const float4* b4 = (const float4*)(beta + row * CC);

    float4 a = o4[li];
    float4 bb = b4[li];
    float4 z = float4{a.x + bb.x, a.y + bb.y, a.z + bb.z, a.w + bb.w};

    float m = fmaxf(fmaxf(z.x, z.y), fmaxf(z.z, z.w));
#pragma unroll
    for (int o = 1; o < 32; o <<= 1) m = fmaxf(m, __shfl_xor(m, o, 64));
    float s = __expf(z.x - m) + __expf(z.y - m) + __expf(z.z - m) + __expf(z.w - m);
#pragma unroll
    for (int o = 1; o < 32; o <<= 1) s += __shfl_xor(s, o, 64);
    float ls = m + __logf(s);
    o4[li] = float4{z.x - ls, z.y - ls, z.z - ls, z.w - ls};
}

// ---------------------------------------------------------------------------
extern "C" void kernel_launch(void* const* d_in, const int* in_sizes, int n_in,
                              void* d_out, int out_size, void* d_ws, size_t ws_size,
                              hipStream_t stream) {
    const float* u_in = (const float*)d_in[0];   // (B, T, C) fp32
    const float* lt   = (const float*)d_in[1];   // (C, C)    fp32
    float*       out  = (float*)d_out;           // (B, T, C) fp32

    float* P    = (float*)d_ws;
    float* PT   = P + CC * CC;
    float* beta = PT + CC * CC;

    prep_kernel<<<CC, CC, 0, stream>>>(lt, P, PT);
    scan_kernel<<<2 * BB * NCH, 256, 0, stream>>>(u_in, P, PT, out, beta);
    combine_kernel<<<(BB * TT) / 8, 256, 0, stream>>>(out, beta);
}

// Round 7
// 173.036 us; speedup vs baseline: 1.5729x; 1.5287x over previous
//
#include <hip/hip_runtime.h>
#include <math.h>

#define BB 16
#define TT 4096
#define CC 128

// R16: MFMA rewrite. R9-R15 established the wall: per-SIMD-step VALU work of
// the 128x128 VALU dot (~1600 busy-cyc/step at EVERY geometry/occupancy;
// R14 asm null, R15 occupancy null). Fix: batch all B=16 chains of one
// (chunk, dir) into one block; per step S(16x128) = E(16x128) x P(128x128)
// via mfma_f32_16x16x32_bf16, fp32 recovered by bf16 hi/lo split
// (3 products, drop lo*lo: rel err ~5e-5). Per-chain scale w[b] =
// x_{s-1}[b][0], lag-1 through LDS -> ONE barrier/step, exp spread <= ~e^41
// (f32-safe). C/D layout: col=lane&15, row=(lane>>4)*4+reg (m89-verified);
// A/B k-mapping errors cancel (same assumed map on both operands).
// LCH=32 -> NCH=128, grid = 2*NCH = 256 blocks (1/CU), NS = LCH+WCH-1 = 79.
#define LCH 32
#define WCH 48
#define NCH (TT / LCH)   // 128

#define ERS 132          // E row stride in u32: 16B-aligned rows, 2-way banks max

typedef float    f32x4  __attribute__((ext_vector_type(4)));
typedef unsigned uint4v __attribute__((ext_vector_type(4)));
typedef __bf16   bf16x8 __attribute__((ext_vector_type(8)));

// ---------------------------------------------------------------------------
// ws layout:
//   [0, 131072 B)                      B-fragments: [dir][T][kc][h][lane][8] bf16
//   [131072 B, +BB*TT*CC*4)            beta
// ---------------------------------------------------------------------------

__device__ __forceinline__ float wave_reduce_max(float v) {
#pragma unroll
    for (int o = 1; o < 64; o <<= 1) v = fmaxf(v, __shfl_xor(v, o, 64));
    return v;
}
__device__ __forceinline__ float wave_reduce_sum(float v) {
#pragma unroll
    for (int o = 1; o < 64; o <<= 1) v += __shfl_xor(v, o, 64);
    return v;
}

// LDS-only barrier: skip the conservative vmcnt(0) drain so global
// prefetch/stores stay in flight across the barrier.
__device__ __forceinline__ void lds_barrier() {
    __asm__ __volatile__("s_waitcnt lgkmcnt(0)" ::: "memory");
    __builtin_amdgcn_s_barrier();
}

// Truncation hi/lo bf16 split, packed hi|lo<<16. hi = top16(f) (trunc);
// lo = f - hi is EXACT in f32; lo trunc error <= 2^-16 * |f|.
__device__ __forceinline__ unsigned pkbf(float f) {
    unsigned u = __float_as_uint(f);
    float hi = __uint_as_float(u & 0xffff0000u);
    float lo = f - hi;
    return (u >> 16) | (__float_as_uint(lo) & 0xffff0000u);
}

// ---------------------------------------------------------------------------
// Prep: P = exp(log_softmax(log_trans, axis=1)); emit MFMA B-fragments for
// both directions, hi/lo split.
//   fwd (dir 0): B[k][n] = P[k][n]  (S[b][j] = sum_i E[b][i] P[i][j])
//   bwd (dir 1): B[k][n] = P[n][k]  (S[b][i] = sum_j E[b][j] P[i][j])
// Fragment of B element (k, n): T=n>>4, kc=k>>5, lane=(((k&31)>>3)<<4)|(n&15),
// e=k&7; slot ((((dir*8+T)*4+kc)*2+h)*64+lane)*8+e.
// ---------------------------------------------------------------------------
__global__ __launch_bounds__(CC) void prep_kernel(const float* __restrict__ lt,
                                                  unsigned short* __restrict__ fr) {
    const int r  = blockIdx.x;
    const int j  = threadIdx.x;
    const int wv = j >> 6;
    __shared__ float sm[2];

    float x = lt[r * CC + j];
    float m = wave_reduce_max(x);
    if ((j & 63) == 0) sm[wv] = m;
    __syncthreads();
    m = fmaxf(sm[0], sm[1]);
    __syncthreads();
    float e = __expf(x - m);
    float s = wave_reduce_sum(e);
    if ((j & 63) == 0) sm[wv] = s;
    __syncthreads();
    s = sm[0] + sm[1];
    float p = e / s;

    unsigned pk = pkbf(p);
    unsigned short phi = (unsigned short)(pk & 0xffffu);
    unsigned short plo = (unsigned short)(pk >> 16);

    {   // dir 0 (fwd): k = r, n = j
        int T = j >> 4, col = j & 15, kc = r >> 5;
        int ln = (((r & 31) >> 3) << 4) | col, e8 = r & 7;
        size_t o = ((((size_t)(0 * 8 + T) * 4 + kc) * 2 + 0) * 64 + ln) * 8 + e8;
        fr[o] = phi; fr[o + 512] = plo;
    }
    {   // dir 1 (bwd): k = j, n = r
        int T = r >> 4, col = r & 15, kc = j >> 5;
        int ln = (((j & 31) >> 3) << 4) | col, e8 = j & 7;
        size_t o = ((((size_t)(1 * 8 + T) * 4 + kc) * 2 + 0) * 64 + ln) * 8 + e8;
        fr[o] = phi; fr[o + 512] = plo;
    }
}

// ---- B fragments: 2 tiles x 4 kc x {hi,lo}, named (static indexing) ----
#define BDECL(T2)                                                              \
    bf16x8 Bh_##T2##_0, Bh_##T2##_1, Bh_##T2##_2, Bh_##T2##_3,                 \
           Bl_##T2##_0, Bl_##T2##_1, Bl_##T2##_2, Bl_##T2##_3

#define BLOAD(T2, kc)                                                          \
    do {                                                                       \
        size_t o = ((((size_t)(dirIdx * 8 + (2 * wv + T2)) * 4 + (kc)) * 2)    \
                        * 64 + lane) * 8;                                      \
        Bh_##T2##_##kc = __builtin_bit_cast(bf16x8, *(const uint4v*)(fr + o)); \
        Bl_##T2##_##kc =                                                       \
            __builtin_bit_cast(bf16x8, *(const uint4v*)(fr + o + 512));        \
    } while (0)

// One K-chunk: 2 b128 LDS reads (8 packed u32), perm-extract hi/lo A-frags,
// 6 MFMAs (2 tiles x {hh, hl, lh}).
#define KC_STEP(kc)                                                            \
    do {                                                                       \
        const uint4v* eptr = (const uint4v*)(epar + arow + (kc) * 32);         \
        uint4v w0 = eptr[0], w1 = eptr[1];                                     \
        uint4v ahw, alw;                                                       \
        ahw.x = __builtin_amdgcn_perm(w0.y, w0.x, 0x05040100u);                \
        ahw.y = __builtin_amdgcn_perm(w0.w, w0.z, 0x05040100u);                \
        ahw.z = __builtin_amdgcn_perm(w1.y, w1.x, 0x05040100u);                \
        ahw.w = __builtin_amdgcn_perm(w1.w, w1.z, 0x05040100u);                \
        alw.x = __builtin_amdgcn_perm(w0.y, w0.x, 0x07060302u);                \
        alw.y = __builtin_amdgcn_perm(w0.w, w0.z, 0x07060302u);                \
        alw.z = __builtin_amdgcn_perm(w1.y, w1.x, 0x07060302u);                \
        alw.w = __builtin_amdgcn_perm(w1.w, w1.z, 0x07060302u);                \
        bf16x8 Ah = __builtin_bit_cast(bf16x8, ahw);                           \
        bf16x8 Al = __builtin_bit_cast(bf16x8, alw);                           \
        acc0 = __builtin_amdgcn_mfma_f32_16x16x32_bf16(Ah, Bh_0_##kc, acc0, 0, 0, 0); \
        acc0 = __builtin_amdgcn_mfma_f32_16x16x32_bf16(Ah, Bl_0_##kc, acc0, 0, 0, 0); \
        acc0 = __builtin_amdgcn_mfma_f32_16x16x32_bf16(Al, Bh_0_##kc, acc0, 0, 0, 0); \
        acc1 = __builtin_amdgcn_mfma_f32_16x16x32_bf16(Ah, Bh_1_##kc, acc1, 0, 0, 0); \
        acc1 = __builtin_amdgcn_mfma_f32_16x16x32_bf16(Ah, Bl_1_##kc, acc1, 0, 0, 0); \
        acc1 = __builtin_amdgcn_mfma_f32_16x16x32_bf16(Al, Bh_1_##kc, acc1, 0, 0, 0); \
    } while (0)

#define LOADU(d0, d1, ROW)                                                     \
    do {                                                                       \
        size_t ro = (size_t)(ROW) * CC;                                        \
        d0.x = ub0[ro + n1]; d0.y = ub1[ro + n1];                              \
        d0.z = ub2[ro + n1]; d0.w = ub3[ro + n1];                              \
        d1.x = ub0[ro + n2]; d1.y = ub1[ro + n2];                              \
        d1.z = ub2[ro + n2]; d1.w = ub3[ro + n2];                              \
    } while (0)

#define STOREO(s0, s1, ROW)                                                    \
    do {                                                                       \
        size_t ro = (size_t)(ROW) * CC;                                        \
        ob0[ro + n1] = s0.x; ob1[ro + n1] = s0.y;                              \
        ob2[ro + n1] = s0.z; ob3[ro + n1] = s0.w;                              \
        ob0[ro + n2] = s1.x; ob1[ro + n2] = s1.y;                              \
        ob2[ro + n2] = s1.z; ob3[ro + n2] = s1.w;                              \
    } while (0)

// ---------------------------------------------------------------------------
// Chunked scan, MFMA contraction, ONE barrier per step.
// Grid = 2*NCH = 256 blocks (1/CU) of 256 threads (4 waves).
//   id < NCH : forward chunk (alpha -> d_out); else backward (beta -> ws).
// Wave wv owns n-tiles {2wv, 2wv+1}; lane holds chains b = (lane>>4)*4+reg,
// cols n1 = 32wv + (lane&15), n2 = n1+16 (= MFMA C/D layout, m89-verified).
// Per step: phase-1 {read w, E=exp(x-w[b]) packed hi|lo -> LDS, publish
// w_{s+1}=x_s[b][0], prefetch u row trow(s+1)}; barrier; phase-2 {A-frags
// from LDS, 24 MFMA, st = (fwd: u+w+logS | bwd: w+logS), store window row,
// x_next = (fwd: st | bwd: st+u)}. E & w double-buffered by parity.
// ---------------------------------------------------------------------------
__global__ __launch_bounds__(256, 1)
void scan_kernel(const float* __restrict__ u,
                 const unsigned short* __restrict__ fr,
                 float* __restrict__ alpha,
                 float* __restrict__ beta) {
    const int t    = threadIdx.x;     // 0..255
    const int lane = t & 63;
    const int wv   = t >> 6;          // wave -> n-tiles {2wv, 2wv+1}
    const int col  = lane & 15;
    const int bb   = (lane >> 4) * 4; // first of this lane's 4 chains
    const int n1   = wv * 32 + col;
    const int n2   = n1 + 16;

    const int  id     = blockIdx.x;
    const bool fwd    = id < NCH;
    const int  c      = fwd ? id : id - NCH;
    const int  dirIdx = fwd ? 0 : 1;

    __shared__ alignas(16) unsigned Epk[2][16 * ERS];
    __shared__ alignas(16) float    wpub[2][16];

    // B fragments (register-resident; MFMA can source VGPR or AGPR).
    BDECL(0); BDECL(1);
    BLOAD(0, 0); BLOAD(0, 1); BLOAD(0, 2); BLOAD(0, 3);
    BLOAD(1, 0); BLOAD(1, 1); BLOAD(1, 2); BLOAD(1, 3);

    const float* ub0 = u + (size_t)(bb + 0) * TT * CC;
    const float* ub1 = u + (size_t)(bb + 1) * TT * CC;
    const float* ub2 = u + (size_t)(bb + 2) * TT * CC;
    const float* ub3 = u + (size_t)(bb + 3) * TT * CC;
    float* obase = fwd ? alpha : beta;
    float* ob0 = obase + (size_t)(bb + 0) * TT * CC;
    float* ob1 = obase + (size_t)(bb + 1) * TT * CC;
    float* ob2 = obase + (size_t)(bb + 2) * TT * CC;
    float* ob3 = obase + (size_t)(bb + 3) * TT * CC;

    const int wlo = c * LCH;
    const int whi = wlo + LCH;
    int t0 = 0, t1 = 0, NS;
    if (fwd) {
        t0 = wlo - WCH; if (t0 < 0) t0 = 0;
        NS = whi - 1 - t0;
    } else {
        t1 = whi - 1 + WCH; if (t1 > TT - 1) t1 = TT - 1;
        NS = t1 - wlo;
    }

    // x = value entering the exp: fwd alpha_t; bwd beta_t + u_t.
    float4 x0, x1, uc0, uc1, un0, un1;
    if (fwd) {
        LOADU(x0, x1, t0);                       // st = u[t0] (exact when t0==0)
        if (t0 == 0 && wlo == 0) STOREO(x0, x1, 0);
    } else {
        LOADU(x0, x1, t1);                       // st = 0 -> x = u[t1]
        if (t1 == whi - 1) {
            float4 z4{0.f, 0.f, 0.f, 0.f};
            STOREO(z4, z4, t1);
        }
    }
    {   // prefetch u row for step 0: trow(0)
        int tr0 = fwd ? (t0 + 1) : (t1 - 1);
        LOADU(un0, un1, tr0);
    }
    // init w for steps 0 and 1: x_0[b][0] (writers: wave 0, col 0)
    if (wv == 0 && col == 0) {
        *(float4*)&wpub[0][(lane >> 4) * 4] = x0;
        *(float4*)&wpub[1][(lane >> 4) * 4] = x0;
    }
    lds_barrier();

    const int arow = (lane & 15) * ERS + (lane >> 4) * 8;

    for (int s = 0; s < NS; ++s) {
        const int par = s & 1;
        unsigned* epar = &Epk[par][0];

        // ---- phase 1: publish E (packed bf16 hi|lo) and w_{s+1} ----
        float4 wmy = *(const float4*)&wpub[par][(lane >> 4) * 4];
        epar[(bb + 0) * ERS + n1] = pkbf(__expf(x0.x - wmy.x));
        epar[(bb + 1) * ERS + n1] = pkbf(__expf(x0.y - wmy.y));
        epar[(bb + 2) * ERS + n1] = pkbf(__expf(x0.z - wmy.z));
        epar[(bb + 3) * ERS + n1] = pkbf(__expf(x0.w - wmy.w));
        epar[(bb + 0) * ERS + n2] = pkbf(__expf(x1.x - wmy.x));
        epar[(bb + 1) * ERS + n2] = pkbf(__expf(x1.y - wmy.y));
        epar[(bb + 2) * ERS + n2] = pkbf(__expf(x1.z - wmy.z));
        epar[(bb + 3) * ERS + n2] = pkbf(__expf(x1.w - wmy.w));
        if (wv == 0 && col == 0)
            *(float4*)&wpub[(s + 1) & 1][(lane >> 4) * 4] = x0;  // lag-1 w

        // slide u pipeline; issue prefetch for trow(s+1) (clamped)
        uc0 = un0; uc1 = un1;
        int trn = fwd ? (t0 + 2 + s) : (t1 - 2 - s);
        if (trn > TT - 1) trn = TT - 1;
        if (trn < 0) trn = 0;
        LOADU(un0, un1, trn);

        lds_barrier();  // E + w published (the ONLY barrier this step)

        // ---- phase 2: S = E x B via MFMA; state update ----
        f32x4 acc0 = {0.f, 0.f, 0.f, 0.f};
        f32x4 acc1 = {0.f, 0.f, 0.f, 0.f};
        KC_STEP(0); KC_STEP(1); KC_STEP(2); KC_STEP(3);

        const int trow = fwd ? (t0 + 1 + s) : (t1 - 1 - s);
        float4 st0, st1;
        if (fwd) {
            st0.x = uc0.x + wmy.x + __logf(acc0.x);
            st0.y = uc0.y + wmy.y + __logf(acc0.y);
            st0.z = uc0.z + wmy.z + __logf(acc0.z);
            st0.w = uc0.w + wmy.w + __logf(acc0.w);
            st1.x = uc1.x + wmy.x + __logf(acc1.x);
            st1.y = uc1.y + wmy.y + __logf(acc1.y);
            st1.z = uc1.z + wmy.z + __logf(acc1.z);
            st1.w = uc1.w + wmy.w + __logf(acc1.w);
            if (trow >= wlo) STOREO(st0, st1, trow);
            x0 = st0; x1 = st1;
        } else {
            st0.x = wmy.x + __logf(acc0.x);
            st0.y = wmy.y + __logf(acc0.y);
            st0.z = wmy.z + __logf(acc0.z);
            st0.w = wmy.w + __logf(acc0.w);
            st1.x = wmy.x + __logf(acc1.x);
            st1.y = wmy.y + __logf(acc1.y);
            st1.z = wmy.z + __logf(acc1.z);
            st1.w = wmy.w + __logf(acc1.w);
            if (trow < whi) STOREO(st0, st1, trow);
            x0.x = st0.x + uc0.x; x0.y = st0.y + uc0.y;
            x0.z = st0.z + uc0.z; x0.w = st0.w + uc0.w;
            x1.x = st1.x + uc1.x; x1.y = st1.y + uc1.y;
            x1.z = st1.z + uc1.z; x1.w = st1.w + uc1.w;
        }
    }
}

// ---------------------------------------------------------------------------
// Combine: out = log_softmax(alpha + beta, axis=-1), in place over d_out.
// float4 per lane; each 32-lane half-wave owns one row (128 floats).
// ---------------------------------------------------------------------------
__global__ __launch_bounds__(256) void combine_kernel(float* __restrict__ out,
                                                      const float* __restrict__ beta) {
    const int    lane = threadIdx.x & 63;
    const int    li   = lane & 31;
    const size_t row  = (size_t)blockIdx.x * 8 + ((threadIdx.x >> 6) << 1) + (lane >> 5);

    float4*       o4 = (float4*)(out + row * CC);
    const float4* b4 = (const float4*)(beta + row * CC);

    float4 a = o4[li];
    float4 bb = b4[li];
    float4 z = float4{a.x + bb.x, a.y + bb.y, a.z + bb.z, a.w + bb.w};

    float m = fmaxf(fmaxf(z.x, z.y), fmaxf(z.z, z.w));
#pragma unroll
    for (int o = 1; o < 32; o <<= 1) m = fmaxf(m, __shfl_xor(m, o, 64));
    float s = __expf(z.x - m) + __expf(z.y - m) + __expf(z.z - m) + __expf(z.w - m);
#pragma unroll
    for (int o = 1; o < 32; o <<= 1) s += __shfl_xor(s, o, 64);
    float ls = m + __logf(s);
    o4[li] = float4{z.x - ls, z.y - ls, z.z - ls, z.w - ls};
}

// ---------------------------------------------------------------------------
extern "C" void kernel_launch(void* const* d_in, const int* in_sizes, int n_in,
                              void* d_out, int out_size, void* d_ws, size_t ws_size,
                              hipStream_t stream) {
    const float* u_in = (const float*)d_in[0];   // (B, T, C) fp32
    const float* lt   = (const float*)d_in[1];   // (C, C)    fp32
    float*       out  = (float*)d_out;           // (B, T, C) fp32

    unsigned short* fr = (unsigned short*)d_ws;          // 131072 B of B-frags
    float* beta = (float*)d_ws + 2 * CC * CC;            // same offset as before

    prep_kernel<<<CC, CC, 0, stream>>>(lt, fr);
    scan_kernel<<<2 * NCH, 256, 0, stream>>>(u_in, fr, out, beta);
    combine_kernel<<<(BB * TT) / 8, 256, 0, stream>>>(out, beta);
}

// Round 8
// 159.565 us; speedup vs baseline: 1.7057x; 1.0844x over previous
//
#include <hip/hip_runtime.h>
#include <math.h>

#define BB 16
#define TT 4096
#define CC 128

// R17: occupancy + chain-split on the R16 MFMA scan.
// R16 measured: 2932 cyc/step at 1 wave/SIMD (Occupancy 10.5%), ~45% of the
// step exposed latency (ds_read ~120, 12-deep serial MFMA accumulate ~360,
// trans chains) that one wave cannot hide. Fix (zero extra work):
//  (a) 512-thread blocks, 8 waves, each wave owns ONE 16-col n-tile ->
//      2 waves/SIMD overlap each other's stalls; per-wave phase work halves.
//  (b) accumulator split into 3 independent 4-deep MFMA chains (HH/HL/LH,
//      summed at the end) instead of one 12-deep serial chain.
// Everything else (operand layouts, lag-1 scale via LDS, hi/lo bf16 split,
// W=48, one barrier/step) is byte-identical to the verified R16 kernel
// (absmax 0.0625).
#define LCH 32
#define WCH 48
#define NCH (TT / LCH)   // 128

#define ERS 132          // E row stride in u32: 16B-aligned rows, low conflicts

typedef float    f32x4  __attribute__((ext_vector_type(4)));
typedef unsigned uint4v __attribute__((ext_vector_type(4)));
typedef __bf16   bf16x8 __attribute__((ext_vector_type(8)));

// ---------------------------------------------------------------------------
// ws layout:
//   [0, 131072 B)                      B-fragments: [dir][T][kc][h][lane][8] bf16
//   [131072 B, +BB*TT*CC*4)            beta
// ---------------------------------------------------------------------------

__device__ __forceinline__ float wave_reduce_max(float v) {
#pragma unroll
    for (int o = 1; o < 64; o <<= 1) v = fmaxf(v, __shfl_xor(v, o, 64));
    return v;
}
__device__ __forceinline__ float wave_reduce_sum(float v) {
#pragma unroll
    for (int o = 1; o < 64; o <<= 1) v += __shfl_xor(v, o, 64);
    return v;
}

// LDS-only barrier: skip the conservative vmcnt(0) drain so global
// prefetch/stores stay in flight across the barrier.
__device__ __forceinline__ void lds_barrier() {
    __asm__ __volatile__("s_waitcnt lgkmcnt(0)" ::: "memory");
    __builtin_amdgcn_s_barrier();
}

// Truncation hi/lo bf16 split, packed hi|lo<<16. hi = top16(f) (trunc);
// lo = f - hi is EXACT in f32; lo trunc error <= 2^-16 * |f|.
__device__ __forceinline__ unsigned pkbf(float f) {
    unsigned u = __float_as_uint(f);
    float hi = __uint_as_float(u & 0xffff0000u);
    float lo = f - hi;
    return (u >> 16) | (__float_as_uint(lo) & 0xffff0000u);
}

// ---------------------------------------------------------------------------
// Prep: P = exp(log_softmax(log_trans, axis=1)); emit MFMA B-fragments for
// both directions, hi/lo split. (Identical to R16.)
//   fwd (dir 0): B[k][n] = P[k][n]   bwd (dir 1): B[k][n] = P[n][k]
// Fragment of B element (k, n): T=n>>4, kc=k>>5, lane=(((k&31)>>3)<<4)|(n&15),
// e=k&7; slot ((((dir*8+T)*4+kc)*2+h)*64+lane)*8+e.
// ---------------------------------------------------------------------------
__global__ __launch_bounds__(CC) void prep_kernel(const float* __restrict__ lt,
                                                  unsigned short* __restrict__ fr) {
    const int r  = blockIdx.x;
    const int j  = threadIdx.x;
    const int wv = j >> 6;
    __shared__ float sm[2];

    float x = lt[r * CC + j];
    float m = wave_reduce_max(x);
    if ((j & 63) == 0) sm[wv] = m;
    __syncthreads();
    m = fmaxf(sm[0], sm[1]);
    __syncthreads();
    float e = __expf(x - m);
    float s = wave_reduce_sum(e);
    if ((j & 63) == 0) sm[wv] = s;
    __syncthreads();
    s = sm[0] + sm[1];
    float p = e / s;

    unsigned pk = pkbf(p);
    unsigned short phi = (unsigned short)(pk & 0xffffu);
    unsigned short plo = (unsigned short)(pk >> 16);

    {   // dir 0 (fwd): k = r, n = j
        int T = j >> 4, col = j & 15, kc = r >> 5;
        int ln = (((r & 31) >> 3) << 4) | col, e8 = r & 7;
        size_t o = ((((size_t)(0 * 8 + T) * 4 + kc) * 2 + 0) * 64 + ln) * 8 + e8;
        fr[o] = phi; fr[o + 512] = plo;
    }
    {   // dir 1 (bwd): k = j, n = r
        int T = r >> 4, col = r & 15, kc = j >> 5;
        int ln = (((j & 31) >> 3) << 4) | col, e8 = j & 7;
        size_t o = ((((size_t)(1 * 8 + T) * 4 + kc) * 2 + 0) * 64 + ln) * 8 + e8;
        fr[o] = phi; fr[o + 512] = plo;
    }
}

// ---- B fragments: this wave's tile (T = wv) x 4 kc x {hi,lo} ----
#define BDECL()                                                                \
    bf16x8 Bh_0, Bh_1, Bh_2, Bh_3, Bl_0, Bl_1, Bl_2, Bl_3

#define BLOAD(kc)                                                              \
    do {                                                                       \
        size_t o = ((((size_t)(dirIdx * 8 + wv) * 4 + (kc)) * 2)               \
                        * 64 + lane) * 8;                                      \
        Bh_##kc = __builtin_bit_cast(bf16x8, *(const uint4v*)(fr + o));        \
        Bl_##kc =                                                              \
            __builtin_bit_cast(bf16x8, *(const uint4v*)(fr + o + 512));        \
    } while (0)

// One K-chunk: 2 b128 LDS reads (8 packed u32), perm-extract hi/lo A-frags,
// 3 MFMAs into 3 INDEPENDENT accumulators (4-deep chains across kc).
#define KC_STEP(kc)                                                            \
    do {                                                                       \
        const uint4v* eptr = (const uint4v*)(epar + arow + (kc) * 32);         \
        uint4v w0 = eptr[0], w1 = eptr[1];                                     \
        uint4v ahw, alw;                                                       \
        ahw.x = __builtin_amdgcn_perm(w0.y, w0.x, 0x05040100u);                \
        ahw.y = __builtin_amdgcn_perm(w0.w, w0.z, 0x05040100u);                \
        ahw.z = __builtin_amdgcn_perm(w1.y, w1.x, 0x05040100u);                \
        ahw.w = __builtin_amdgcn_perm(w1.w, w1.z, 0x05040100u);                \
        alw.x = __builtin_amdgcn_perm(w0.y, w0.x, 0x07060302u);                \
        alw.y = __builtin_amdgcn_perm(w0.w, w0.z, 0x07060302u);                \
        alw.z = __builtin_amdgcn_perm(w1.y, w1.x, 0x07060302u);                \
        alw.w = __builtin_amdgcn_perm(w1.w, w1.z, 0x07060302u);                \
        bf16x8 Ah = __builtin_bit_cast(bf16x8, ahw);                           \
        bf16x8 Al = __builtin_bit_cast(bf16x8, alw);                           \
        accHH = __builtin_amdgcn_mfma_f32_16x16x32_bf16(Ah, Bh_##kc, accHH, 0, 0, 0); \
        accHL = __builtin_amdgcn_mfma_f32_16x16x32_bf16(Ah, Bl_##kc, accHL, 0, 0, 0); \
        accLH = __builtin_amdgcn_mfma_f32_16x16x32_bf16(Al, Bh_##kc, accLH, 0, 0, 0); \
    } while (0)

#define LOADU(d0, ROW)                                                         \
    do {                                                                       \
        size_t ro = (size_t)(ROW) * CC;                                        \
        d0.x = ub0[ro + n1]; d0.y = ub1[ro + n1];                              \
        d0.z = ub2[ro + n1]; d0.w = ub3[ro + n1];                              \
    } while (0)

#define STOREO(s0, ROW)                                                        \
    do {                                                                       \
        size_t ro = (size_t)(ROW) * CC;                                        \
        ob0[ro + n1] = s0.x; ob1[ro + n1] = s0.y;                              \
        ob2[ro + n1] = s0.z; ob3[ro + n1] = s0.w;                              \
    } while (0)

// ---------------------------------------------------------------------------
// Chunked scan, MFMA contraction, ONE barrier per step.
// Grid = 2*NCH = 256 blocks (1/CU) of 512 threads (8 waves = 2 waves/SIMD).
//   id < NCH : forward chunk (alpha -> d_out); else backward (beta -> ws).
// Wave wv owns n-tile wv; lane holds chains b = (lane>>4)*4+reg, col
// n1 = 16wv + (lane&15) (= MFMA C/D layout, m89-verified).
// Per step: phase-1 {read w, E=exp(x-w[b]) packed hi|lo -> LDS, publish
// w_{s+1}=x_s[b][0], prefetch u row trow(s+1)}; barrier; phase-2 {A-frags
// from LDS, 12 MFMA in 3 independent chains, st = (fwd: u+w+logS |
// bwd: w+logS), store window row, x_next = (fwd: st | bwd: st+u)}.
// E & w double-buffered by parity.
// ---------------------------------------------------------------------------
__global__ __launch_bounds__(512, 1)
void scan_kernel(const float* __restrict__ u,
                 const unsigned short* __restrict__ fr,
                 float* __restrict__ alpha,
                 float* __restrict__ beta) {
    const int t    = threadIdx.x;     // 0..511
    const int lane = t & 63;
    const int wv   = t >> 6;          // wave -> n-tile wv
    const int col  = lane & 15;
    const int bb   = (lane >> 4) * 4; // first of this lane's 4 chains
    const int n1   = wv * 16 + col;

    const int  id     = blockIdx.x;
    const bool fwd    = id < NCH;
    const int  c      = fwd ? id : id - NCH;
    const int  dirIdx = fwd ? 0 : 1;

    __shared__ alignas(16) unsigned Epk[2][16 * ERS];
    __shared__ alignas(16) float    wpub[2][16];

    // B fragments (register-resident; MFMA can source VGPR or AGPR).
    BDECL();
    BLOAD(0); BLOAD(1); BLOAD(2); BLOAD(3);

    const float* ub0 = u + (size_t)(bb + 0) * TT * CC;
    const float* ub1 = u + (size_t)(bb + 1) * TT * CC;
    const float* ub2 = u + (size_t)(bb + 2) * TT * CC;
    const float* ub3 = u + (size_t)(bb + 3) * TT * CC;
    float* obase = fwd ? alpha : beta;
    float* ob0 = obase + (size_t)(bb + 0) * TT * CC;
    float* ob1 = obase + (size_t)(bb + 1) * TT * CC;
    float* ob2 = obase + (size_t)(bb + 2) * TT * CC;
    float* ob3 = obase + (size_t)(bb + 3) * TT * CC;

    const int wlo = c * LCH;
    const int whi = wlo + LCH;
    int t0 = 0, t1 = 0, NS;
    if (fwd) {
        t0 = wlo - WCH; if (t0 < 0) t0 = 0;
        NS = whi - 1 - t0;
    } else {
        t1 = whi - 1 + WCH; if (t1 > TT - 1) t1 = TT - 1;
        NS = t1 - wlo;
    }

    // x = value entering the exp: fwd alpha_t; bwd beta_t + u_t.
    float4 x0, uc0, un0;
    if (fwd) {
        LOADU(x0, t0);                           // st = u[t0] (exact when t0==0)
        if (t0 == 0 && wlo == 0) STOREO(x0, 0);
    } else {
        LOADU(x0, t1);                           // st = 0 -> x = u[t1]
        if (t1 == whi - 1) {
            float4 z4{0.f, 0.f, 0.f, 0.f};
            STOREO(z4, t1);
        }
    }
    {   // prefetch u row for step 0: trow(0)
        int tr0 = fwd ? (t0 + 1) : (t1 - 1);
        LOADU(un0, tr0);
    }
    // init w for steps 0 and 1: x_0[b][0] (writers: wave 0, col 0)
    if (wv == 0 && col == 0) {
        *(float4*)&wpub[0][bb] = x0;
        *(float4*)&wpub[1][bb] = x0;
    }
    lds_barrier();

    const int arow = (lane & 15) * ERS + (lane >> 4) * 8;

    for (int s = 0; s < NS; ++s) {
        const int par = s & 1;
        unsigned* epar = &Epk[par][0];

        // ---- phase 1: publish E (packed bf16 hi|lo) and w_{s+1} ----
        float4 wmy = *(const float4*)&wpub[par][bb];
        epar[(bb + 0) * ERS + n1] = pkbf(__expf(x0.x - wmy.x));
        epar[(bb + 1) * ERS + n1] = pkbf(__expf(x0.y - wmy.y));
        epar[(bb + 2) * ERS + n1] = pkbf(__expf(x0.z - wmy.z));
        epar[(bb + 3) * ERS + n1] = pkbf(__expf(x0.w - wmy.w));
        if (wv == 0 && col == 0)
            *(float4*)&wpub[(s + 1) & 1][bb] = x0;   // lag-1 w

        // slide u pipeline; issue prefetch for trow(s+1) (clamped)
        uc0 = un0;
        int trn = fwd ? (t0 + 2 + s) : (t1 - 2 - s);
        if (trn > TT - 1) trn = TT - 1;
        if (trn < 0) trn = 0;
        LOADU(un0, trn);

        lds_barrier();  // E + w published (the ONLY barrier this step)

        // ---- phase 2: S = E x B via MFMA (3 independent 4-deep chains) ----
        f32x4 accHH = {0.f, 0.f, 0.f, 0.f};
        f32x4 accHL = {0.f, 0.f, 0.f, 0.f};
        f32x4 accLH = {0.f, 0.f, 0.f, 0.f};
        KC_STEP(0); KC_STEP(1); KC_STEP(2); KC_STEP(3);
        f32x4 acc0 = (accHH + accHL) + accLH;

        const int trow = fwd ? (t0 + 1 + s) : (t1 - 1 - s);
        float4 st0;
        if (fwd) {
            st0.x = uc0.x + wmy.x + __logf(acc0.x);
            st0.y = uc0.y + wmy.y + __logf(acc0.y);
            st0.z = uc0.z + wmy.z + __logf(acc0.z);
            st0.w = uc0.w + wmy.w + __logf(acc0.w);
            if (trow >= wlo) STOREO(st0, trow);
            x0 = st0;
        } else {
            st0.x = wmy.x + __logf(acc0.x);
            st0.y = wmy.y + __logf(acc0.y);
            st0.z = wmy.z + __logf(acc0.z);
            st0.w = wmy.w + __logf(acc0.w);
            if (trow < whi) STOREO(st0, trow);
            x0.x = st0.x + uc0.x; x0.y = st0.y + uc0.y;
            x0.z = st0.z + uc0.z; x0.w = st0.w + uc0.w;
        }
    }
}

// ---------------------------------------------------------------------------
// Combine: out = log_softmax(alpha + beta, axis=-1), in place over d_out.
// float4 per lane; each 32-lane half-wave owns one row (128 floats).
// ---------------------------------------------------------------------------
__global__ __launch_bounds__(256) void combine_kernel(float* __restrict__ out,
                                                      const float* __restrict__ beta) {
    const int    lane = threadIdx.x & 63;
    const int    li   = lane & 31;
    const size_t row  = (size_t)blockIdx.x * 8 + ((threadIdx.x >> 6) << 1) + (lane >> 5);

    float4*       o4 = (float4*)(out + row * CC);
    const float4* b4 = (const float4*)(beta + row * CC);

    float4 a = o4[li];
    float4 bb = b4[li];
    float4 z = float4{a.x + bb.x, a.y + bb.y, a.z + bb.z, a.w + bb.w};

    float m = fmaxf(fmaxf(z.x, z.y), fmaxf(z.z, z.w));
#pragma unroll
    for (int o = 1; o < 32; o <<= 1) m = fmaxf(m, __shfl_xor(m, o, 64));
    float s = __expf(z.x - m) + __expf(z.y - m) + __expf(z.z - m) + __expf(z.w - m);
#pragma unroll
    for (int o = 1; o < 32; o <<= 1) s += __shfl_xor(s, o, 64);
    float ls = m + __logf(s);
    o4[li] = float4{z.x - ls, z.y - ls, z.z - ls, z.w - ls};
}

// ---------------------------------------------------------------------------
extern "C" void kernel_launch(void* const* d_in, const int* in_sizes, int n_in,
                              void* d_out, int out_size, void* d_ws, size_t ws_size,
                              hipStream_t stream) {
    const float* u_in = (const float*)d_in[0];   // (B, T, C) fp32
    const float* lt   = (const float*)d_in[1];   // (C, C)    fp32
    float*       out  = (float*)d_out;           // (B, T, C) fp32

    unsigned short* fr = (unsigned short*)d_ws;          // 131072 B of B-frags
    float* beta = (float*)d_ws + 2 * CC * CC;            // same offset as before

    prep_kernel<<<CC, CC, 0, stream>>>(lt, fr);
    scan_kernel<<<2 * NCH, 512, 0, stream>>>(u_in, fr, out, beta);
    combine_kernel<<<(BB * TT) / 8, 256, 0, stream>>>(out, beta);
}